// Round 2
// baseline (1507.874 us; speedup 1.0000x reference)
//
#include <hip/hip_runtime.h>
#include <math.h>

#define DEVI __device__ __forceinline__
typedef unsigned short u16;
typedef unsigned int u32;
typedef __bf16 bf16x8 __attribute__((ext_vector_type(8)));
typedef float f32x4 __attribute__((ext_vector_type(4)));

static constexpr int CAP = 8192;   // per (router,rank,expert) list capacity

DEVI u16 f2b(float f) {            // f32 -> bf16 bits, RNE
  u32 x = __builtin_bit_cast(u32, f);
  u32 r = (x + 0x7fffu + ((x >> 16) & 1u)) >> 16;
  return (u16)r;
}
DEVI float b2f(u16 u) { return __builtin_bit_cast(float, (u32)u << 16); }

DEVI void async16(const u16* g, u16* l) {
  __builtin_amdgcn_global_load_lds((__attribute__((address_space(1))) void*)g,
                                   (__attribute__((address_space(3))) void*)l, 16, 0, 0);
}

DEVI double dot4d(float4 a, float4 b) {
  return (double)a.x * b.x + (double)a.y * b.y + (double)a.z * b.z + (double)a.w * b.w;
}

// ---------------- f32 -> bf16 conversion (two source ranges) ----------------
__global__ void cvt_k(const float* __restrict__ s0, u16* __restrict__ d0, long n0,
                      const float* __restrict__ s1, u16* __restrict__ d1, long n1) {
  long nq0 = n0 / 4, nq = (n0 + n1) / 4;
  long stride = (long)gridDim.x * blockDim.x;
  for (long q = (long)blockIdx.x * blockDim.x + threadIdx.x; q < nq; q += stride) {
    long qi = q; const float* s = s0; u16* d = d0;
    if (qi >= nq0) { qi -= nq0; s = s1; d = d1; }
    float4 v = ((const float4*)s)[qi];
    ushort4 o;
    o.x = f2b(v.x); o.y = f2b(v.y); o.z = f2b(v.z); o.w = f2b(v.w);
    ((ushort4*)d)[qi] = o;
  }
}

// ---------------- router: x_addr (f64), z (f64), top3+softmax, lists, bias ----------------
__global__ __launch_bounds__(256) void router_k(
    const float* __restrict__ x, const float* __restrict__ Pw,
    const float* __restrict__ U1, const float* __restrict__ U2, const float* __restrict__ U3,
    const float* __restrict__ b2,
    int* __restrict__ cnt, int* __restrict__ ltok, float* __restrict__ lwgt,
    float* __restrict__ out) {
  __shared__ double sxa[16][65];
  __shared__ double sz[16][40];
  __shared__ int se[16][3];
  __shared__ float sw[16][3];

  const int tid = threadIdx.x;
  const int tok0 = blockIdx.x * 16;

  { // x_addr in f64: thread (tt, g) computes dims 4g..4g+3 for token tt
    const int tt = tid & 15, g = tid >> 4;
    const float* xr = x + (size_t)(tok0 + tt) * 1024;
    const float* p0 = Pw + (size_t)(4 * g) * 1024;
    double a0 = 0, a1 = 0, a2 = 0, a3 = 0;
    for (int k = 0; k < 1024; k += 4) {
      float4 xv = *(const float4*)(xr + k);
      float4 q0 = *(const float4*)(p0 + k);
      float4 q1 = *(const float4*)(p0 + 1024 + k);
      float4 q2 = *(const float4*)(p0 + 2048 + k);
      float4 q3 = *(const float4*)(p0 + 3072 + k);
      a0 += dot4d(xv, q0); a1 += dot4d(xv, q1);
      a2 += dot4d(xv, q2); a3 += dot4d(xv, q3);
    }
    sxa[tt][4 * g + 0] = a0; sxa[tt][4 * g + 1] = a1;
    sxa[tt][4 * g + 2] = a2; sxa[tt][4 * g + 3] = a3;
  }
  __syncthreads();

  // z[tok][r][e] = xa . U_r[e]
  for (int base = 0; base < 48; base += 16) {
    int re = base + (tid >> 4);
    if (re < 36) {
      int r = re / 12, e = re % 12, tt = tid & 15;
      const float* U = (r == 0 ? U1 : (r == 1 ? U2 : U3)) + e * 64;
      double acc = 0;
      for (int k = 0; k < 64; ++k) acc += sxa[tt][k] * (double)U[k];
      sz[tt][re] = acc;
    }
  }
  __syncthreads();

  if (tid < 48) { // top-3 + softmax per (token, router)
    const int tt = tid & 15, r = tid >> 4;
    const double* z = &sz[tt][r * 12];
    double v0 = -1e300, v1 = -1e300, v2 = -1e300;
    int i0 = 0, i1 = 0, i2 = 0;
    for (int e = 0; e < 12; ++e) {
      double v = z[e];
      if (v > v0)      { v2 = v1; i2 = i1; v1 = v0; i1 = i0; v0 = v; i0 = e; }
      else if (v > v1) { v2 = v1; i2 = i1; v1 = v; i1 = e; }
      else if (v > v2) { v2 = v; i2 = e; }
    }
    const double inv_tau = 1.0 / (1.0 + 1e-8);
    double e1 = exp((v1 - v0) * inv_tau), e2 = exp((v2 - v0) * inv_tau);
    double s = 1.0 / (1.0 + e1 + e2);
    double w0 = s, w1 = e1 * s, w2 = e2 * s;
    int n = tok0 + tt;
    if (r < 2) {
      int jj[3] = { i0, i1, i2 };
      double ww[3] = { w0, w1, w2 };
      for (int j = 0; j < 3; ++j) {
        int slot = (r * 3 + j) * 12 + jj[j];
        int pos = atomicAdd(&cnt[slot], 1);
        ltok[slot * CAP + pos] = n;
        lwgt[slot * CAP + pos] = (float)ww[j];
      }
    } else {
      se[tt][0] = i0; se[tt][1] = i1; se[tt][2] = i2;
      sw[tt][0] = (float)w0; sw[tt][1] = (float)w1; sw[tt][2] = (float)w2;
    }
  }
  __syncthreads();

  { // bias init of d_out (f32): out[n] = sum_j w3_j * b2[e3_j]
    const int tt = tid >> 4, cg = tid & 15;
    const int n = tok0 + tt;
    const float* r0 = b2 + (size_t)se[tt][0] * 1024;
    const float* r1 = b2 + (size_t)se[tt][1] * 1024;
    const float* r2 = b2 + (size_t)se[tt][2] * 1024;
    const float w0 = sw[tt][0], w1 = sw[tt][1], w2 = sw[tt][2];
    float* op = out + (size_t)n * 1024;
    for (int c = cg * 64; c < cg * 64 + 64; c += 4) {
      float4 a = *(const float4*)(r0 + c);
      float4 b = *(const float4*)(r1 + c);
      float4 d = *(const float4*)(r2 + c);
      float4 o;
      o.x = w0 * a.x + w1 * b.x + w2 * d.x;
      o.y = w0 * a.y + w1 * b.y + w2 * d.y;
      o.z = w0 * a.z + w1 * b.z + w2 * d.z;
      o.w = w0 * a.w + w1 * b.w + w2 * d.w;
      *(float4*)(op + c) = o;
    }
  }
}

// ---------------- tile descriptor build ----------------
__global__ void build_k(const int* __restrict__ cnt, int2* __restrict__ desc,
                        int* __restrict__ ntl) {
  int t = threadIdx.x;
  if (t < 6) {
    int nt = 0;
    for (int e = 0; e < 12; ++e) {
      int c = cnt[t * 12 + e];
      for (int s = 0; s < c; s += 128) { desc[t * 80 + nt] = make_int2(e, s); ++nt; }
    }
    ntl[t] = nt;
  }
}

// ---------------- grouped GEMM pass (m97 structure, gathered A, scattered C) ----------------
// CT = u16 (bf16 RMW, used for h) or float (f32 RMW, used for d_out)
template<int K, int NOUT, bool ADD, typename CT>
__global__ __launch_bounds__(256) void moe_gemm(
    const u16* __restrict__ A, const u16* __restrict__ W, CT* __restrict__ C,
    const int* __restrict__ cnt12, const int* __restrict__ ltok12,
    const float* __restrict__ lwgt12,
    const int2* __restrict__ desc, const int* __restrict__ ntl) {
  if ((int)blockIdx.x >= *ntl) return;
  const int2 dd = desc[blockIdx.x];
  const int e = dd.x, rowStart = dd.y;
  const int rows = min(128, cnt12[e] - rowStart);
  const int ntile = blockIdx.y;

  __shared__ __align__(16) u16 As[128 * 64];
  __shared__ __align__(16) u16 Bs[128 * 64];
  __shared__ int tokL[128];
  __shared__ float wgtL[128];

  const int tid = threadIdx.x;
  const int lane = tid & 63, w = tid >> 6;
  if (tid < 128) {
    int li = min(tid, rows - 1);
    tokL[tid] = ltok12[e * CAP + rowStart + li];
    wgtL[tid] = lwgt12[e * CAP + rowStart + li];
  }
  __syncthreads();

  const u16* aSrc[4]; const u16* bSrc[4];
#pragma unroll
  for (int i = 0; i < 4; ++i) {
    int r = (w * 4 + i) * 8 + (lane >> 3);
    aSrc[i] = A + (size_t)tokL[r] * K + (lane & 7) * 8;
    bSrc[i] = W + ((size_t)e * NOUT + ntile * 128 + r) * K + (lane & 7) * 8;
  }

  f32x4 acc[4][4] = {};
  const int wr = w >> 1, wc = w & 1;

  for (int kt = 0; kt < K / 64; ++kt) {
#pragma unroll
    for (int i = 0; i < 4; ++i) {
      int c = w * 4 + i;
      async16(aSrc[i] + kt * 64, &As[c * 512]);
      async16(bSrc[i] + kt * 64, &Bs[c * 512]);
    }
    asm volatile("s_waitcnt vmcnt(0)" ::: "memory");
    __syncthreads();
#pragma unroll
    for (int kk = 0; kk < 2; ++kk) {
      bf16x8 af[4], bfr[4];
#pragma unroll
      for (int mi = 0; mi < 4; ++mi) {
        int rowA = wr * 64 + mi * 16 + (lane & 15);
        af[mi] = *(const bf16x8*)&As[rowA * 64 + kk * 32 + (lane >> 4) * 8];
      }
#pragma unroll
      for (int ni = 0; ni < 4; ++ni) {
        int rowB = wc * 64 + ni * 16 + (lane & 15);
        bfr[ni] = *(const bf16x8*)&Bs[rowB * 64 + kk * 32 + (lane >> 4) * 8];
      }
#pragma unroll
      for (int mi = 0; mi < 4; ++mi)
#pragma unroll
        for (int ni = 0; ni < 4; ++ni)
          acc[mi][ni] = __builtin_amdgcn_mfma_f32_16x16x32_bf16(af[mi], bfr[ni], acc[mi][ni], 0, 0, 0);
    }
    __syncthreads();
  }

  // epilogue: scaled scatter (RMW; bf16 for h, f32 for d_out)
#pragma unroll
  for (int mi = 0; mi < 4; ++mi) {
    int lr0 = wr * 64 + mi * 16 + ((lane >> 4) << 2);
#pragma unroll
    for (int rr = 0; rr < 4; ++rr) {
      int lrow = lr0 + rr;
      if (lrow < rows) {
        int tok = tokL[lrow];
        float wv = wgtL[lrow];
        CT* cp = C + (size_t)tok * NOUT + ntile * 128 + wc * 64 + (lane & 15);
#pragma unroll
        for (int ni = 0; ni < 4; ++ni) {
          float val = acc[mi][ni][rr] * wv;
          CT* p = cp + ni * 16;
          if constexpr (sizeof(CT) == 2) {
            float res = ADD ? (b2f(*p) + val) : val;
            *p = f2b(res);
          } else {
            float res = ADD ? (*p + val) : val;
            *p = res;
          }
        }
      }
    }
  }
}

// ---------------- exact GELU in-place on bf16 h ----------------
DEVI float gelu1(float v) { return 0.5f * v * (1.0f + erff(v * 0.70710678118654752f)); }
DEVI u32 gpair(u32 u) {
  float lo = __builtin_bit_cast(float, (u & 0xffffu) << 16);
  float hi = __builtin_bit_cast(float, u & 0xffff0000u);
  return (u32)f2b(gelu1(lo)) | ((u32)f2b(gelu1(hi)) << 16);
}
__global__ void gelu_k(u32* __restrict__ h, long n4) { // n4 = count of uint4 groups
  long stride = (long)gridDim.x * blockDim.x;
  uint4* p = (uint4*)h;
  for (long i = (long)blockIdx.x * blockDim.x + threadIdx.x; i < n4; i += stride) {
    uint4 v = p[i];
    v.x = gpair(v.x); v.y = gpair(v.y); v.z = gpair(v.z); v.w = gpair(v.w);
    p[i] = v;
  }
}

extern "C" void kernel_launch(void* const* d_in, const int* in_sizes, int n_in,
                              void* d_out, int out_size, void* d_ws, size_t ws_size,
                              hipStream_t stream) {
  const float* x  = (const float*)d_in[0];
  const float* Pw = (const float*)d_in[1];
  const float* U1 = (const float*)d_in[2];
  const float* U2 = (const float*)d_in[3];
  const float* U3 = (const float*)d_in[4];
  const float* W1 = (const float*)d_in[5];
  const float* W2 = (const float*)d_in[6];
  const float* b2 = (const float*)d_in[7];
  float* out = (float*)d_out;

  char* ws = (char*)d_ws;
  size_t o = 0;
  u16* Wb = (u16*)(ws + o); o += (size_t)12 * 4096 * 1024 * 2;  // W1b, later W2b
  u16* xb = (u16*)(ws + o); o += (size_t)8192 * 1024 * 2;
  u16* h  = (u16*)(ws + o); o += (size_t)8192 * 4096 * 2;
  int* cnt = (int*)(ws + o); o += 512;
  int2* desc = (int2*)(ws + o); o += (size_t)6 * 80 * sizeof(int2);
  o = (o + 255) & ~(size_t)255;
  int* ntl = (int*)(ws + o); o += 256;
  int* ltok = (int*)(ws + o); o += (size_t)6 * 12 * CAP * 4;
  float* lwgt = (float*)(ws + o); o += (size_t)6 * 12 * CAP * 4;
  if (ws_size < o) return;  // signature: untouched output

  hipMemsetAsync(cnt, 0, 512, stream);
  cvt_k<<<4096, 256, 0, stream>>>(W1, Wb, (long)12 * 4096 * 1024, x, xb, (long)8192 * 1024);
  router_k<<<512, 256, 0, stream>>>(x, Pw, U1, U2, U3, b2, cnt, ltok, lwgt, out);
  build_k<<<1, 64, 0, stream>>>(cnt, desc, ntl);

  { // layer 1: h = sum over ranks of w * (x @ W1[e]^T)   (bf16 RMW in ws)
    dim3 g(80, 32);
    int s;
    s = 0; moe_gemm<1024, 4096, false, u16><<<g, 256, 0, stream>>>(xb, Wb, h, cnt + s * 12, ltok + (size_t)s * 12 * CAP, lwgt + (size_t)s * 12 * CAP, desc + s * 80, ntl + s);
    s = 1; moe_gemm<1024, 4096, true , u16><<<g, 256, 0, stream>>>(xb, Wb, h, cnt + s * 12, ltok + (size_t)s * 12 * CAP, lwgt + (size_t)s * 12 * CAP, desc + s * 80, ntl + s);
    s = 2; moe_gemm<1024, 4096, true , u16><<<g, 256, 0, stream>>>(xb, Wb, h, cnt + s * 12, ltok + (size_t)s * 12 * CAP, lwgt + (size_t)s * 12 * CAP, desc + s * 80, ntl + s);
  }

  // convert W2 into the same weight buffer (after layer-1 passes)
  cvt_k<<<4096, 256, 0, stream>>>(W2, Wb, (long)12 * 1024 * 4096, nullptr, nullptr, 0);
  gelu_k<<<2048, 256, 0, stream>>>((u32*)h, (long)8192 * 4096 / 8);

  { // layer 2: out += sum over ranks of w * (gelu(h) @ W2[e]^T)   (bias already in out, f32)
    dim3 g(80, 8);
    int s;
    s = 3; moe_gemm<4096, 1024, true, float><<<g, 256, 0, stream>>>(h, Wb, out, cnt + s * 12, ltok + (size_t)s * 12 * CAP, lwgt + (size_t)s * 12 * CAP, desc + s * 80, ntl + s);
    s = 4; moe_gemm<4096, 1024, true, float><<<g, 256, 0, stream>>>(h, Wb, out, cnt + s * 12, ltok + (size_t)s * 12 * CAP, lwgt + (size_t)s * 12 * CAP, desc + s * 80, ntl + s);
    s = 5; moe_gemm<4096, 1024, true, float><<<g, 256, 0, stream>>>(h, Wb, out, cnt + s * 12, ltok + (size_t)s * 12 * CAP, lwgt + (size_t)s * 12 * CAP, desc + s * 80, ntl + s);
  }
}

// Round 3
// 1380.937 us; speedup vs baseline: 1.0919x; 1.0919x over previous
//
#include <hip/hip_runtime.h>
#include <math.h>

#define DEVI __device__ __forceinline__
typedef unsigned short u16;
typedef unsigned int u32;
typedef __bf16 bf16x8 __attribute__((ext_vector_type(8)));
typedef float f32x4 __attribute__((ext_vector_type(4)));

static constexpr int CAP = 8192;   // per (router,rank,expert) list capacity

DEVI u16 f2b(float f) {            // f32 -> bf16 bits, RNE
  u32 x = __builtin_bit_cast(u32, f);
  u32 r = (x + 0x7fffu + ((x >> 16) & 1u)) >> 16;
  return (u16)r;
}
DEVI float b2f(u16 u) { return __builtin_bit_cast(float, (u32)u << 16); }

DEVI void async16(const u16* g, u16* l) {
  __builtin_amdgcn_global_load_lds((__attribute__((address_space(1))) void*)g,
                                   (__attribute__((address_space(3))) void*)l, 16, 0, 0);
}

// ---------------- f32 -> bf16 conversion ----------------
__global__ void cvt_k(const float* __restrict__ s0, u16* __restrict__ d0, long n0) {
  long nq = n0 / 4;
  long stride = (long)gridDim.x * blockDim.x;
  for (long q = (long)blockIdx.x * blockDim.x + threadIdx.x; q < nq; q += stride) {
    float4 v = ((const float4*)s0)[q];
    ushort4 o;
    o.x = f2b(v.x); o.y = f2b(v.y); o.z = f2b(v.z); o.w = f2b(v.w);
    ((ushort4*)d0)[q] = o;
  }
}

// ---------------- router: coalesced LDS-tiled, f64 accumulation ----------------
// block = 32 tokens, 256 threads. Thread (tt2=tid&15, dg=tid>>4) owns
// tokens {2*tt2, 2*tt2+1} x dims {4*dg..4*dg+3}.  Also emits xb (bf16 x).
__global__ __launch_bounds__(256) void router_k(
    const float* __restrict__ x, const float* __restrict__ Pw,
    const float* __restrict__ U1, const float* __restrict__ U2, const float* __restrict__ U3,
    const float* __restrict__ b2,
    int* __restrict__ cnt, int* __restrict__ ltok, float* __restrict__ lwgt,
    float* __restrict__ out, u16* __restrict__ xb) {
  __shared__ __align__(16) char sm[54592];
  float*  xs  = (float*)sm;                       // [32][132] f32
  float*  pws = (float*)(sm + 16896);             // [64][132] f32   (stage A)
  double* xa  = (double*)(sm + 16896);            // [32][66]  f64   (stage B, aliases pws)
  double* zz  = (double*)(sm + 16896 + 16896);    // [32][40]  f64
  float*  us  = (float*)(sm + 16896 + 27136);     // [36][68]  f32
  int*    se  = (int*)(sm + 16896 + 36928);       // [32][3]
  float*  swg = (float*)(sm + 16896 + 37312);     // [32][3]

  const int tid = threadIdx.x;
  const int tok0 = blockIdx.x * 32;
  const int tt2 = tid & 15, dg = tid >> 4;

  double acc[2][4] = {{0, 0, 0, 0}, {0, 0, 0, 0}};

  for (int kc = 0; kc < 8; ++kc) {
#pragma unroll
    for (int j = 0; j < 4; ++j) {         // stage x chunk [32][128] + emit bf16
      int f = tid + 256 * j;
      int t = f >> 5, c4 = f & 31;
      size_t goff = (size_t)(tok0 + t) * 1024 + kc * 128 + c4 * 4;
      float4 v = *(const float4*)&x[goff];
      *(float4*)&xs[t * 132 + c4 * 4] = v;
      ushort4 o; o.x = f2b(v.x); o.y = f2b(v.y); o.z = f2b(v.z); o.w = f2b(v.w);
      *(ushort4*)&xb[goff] = o;
    }
#pragma unroll
    for (int j = 0; j < 8; ++j) {         // stage Pw chunk [64][128]
      int f = tid + 256 * j;
      int r = f >> 5, c4 = f & 31;
      *(float4*)&pws[r * 132 + c4 * 4] = *(const float4*)&Pw[(size_t)r * 1024 + kc * 128 + c4 * 4];
    }
    __syncthreads();
    for (int k = 0; k < 128; k += 4) {
      float4 xv0 = *(const float4*)&xs[(tt2 * 2 + 0) * 132 + k];
      float4 xv1 = *(const float4*)&xs[(tt2 * 2 + 1) * 132 + k];
#pragma unroll
      for (int i = 0; i < 4; ++i) {
        float4 p = *(const float4*)&pws[(dg * 4 + i) * 132 + k];
        acc[0][i] += (double)xv0.x * p.x + (double)xv0.y * p.y + (double)xv0.z * p.z + (double)xv0.w * p.w;
        acc[1][i] += (double)xv1.x * p.x + (double)xv1.y * p.y + (double)xv1.z * p.z + (double)xv1.w * p.w;
      }
    }
    __syncthreads();
  }

  // write x_addr to LDS (aliases pws - all reads done) + stage U rows
#pragma unroll
  for (int j = 0; j < 2; ++j)
#pragma unroll
    for (int i = 0; i < 4; ++i)
      xa[(tt2 * 2 + j) * 66 + dg * 4 + i] = acc[j][i];
  if (tid < 144) {                        // 36 rows x 16 float4 = 576; 256thr: first 144 do 4 each
#pragma unroll
    for (int j = 0; j < 4; ++j) {
      int f = tid * 4 + j;                // 0..575
      int r = f >> 4, c4 = f & 15;
      const float* U = (r < 12) ? (U1 + r * 64) : (r < 24 ? U2 + (r - 12) * 64 : U3 + (r - 24) * 64);
      *(float4*)&us[r * 68 + c4 * 4] = *(const float4*)&U[c4 * 4];
    }
  }
  __syncthreads();

  { // z[tok][re] in f64
    const int tok = tid >> 3, jj = tid & 7;
#pragma unroll
    for (int m = 0; m < 5; ++m) {
      int re = jj + 8 * m;
      if (re < 36) {
        double a = 0;
        for (int k = 0; k < 64; ++k)
          a += xa[tok * 66 + k] * (double)us[re * 68 + k];
        zz[tok * 40 + re] = a;
      }
    }
  }
  __syncthreads();

  if (tid < 96) {  // top-3 + softmax per (token, router)
    const int tok = tid & 31, r = tid >> 5;
    const double* z = &zz[tok * 40 + r * 12];
    double v0 = -1e300, v1 = -1e300, v2 = -1e300;
    int i0 = 0, i1 = 0, i2 = 0;
    for (int e = 0; e < 12; ++e) {
      double v = z[e];
      if (v > v0)      { v2 = v1; i2 = i1; v1 = v0; i1 = i0; v0 = v; i0 = e; }
      else if (v > v1) { v2 = v1; i2 = i1; v1 = v; i1 = e; }
      else if (v > v2) { v2 = v; i2 = e; }
    }
    const double inv_tau = 1.0 / (1.0 + 1e-8);
    double e1 = exp((v1 - v0) * inv_tau), e2 = exp((v2 - v0) * inv_tau);
    double s = 1.0 / (1.0 + e1 + e2);
    double w0 = s, w1 = e1 * s, w2 = e2 * s;
    int n = tok0 + tok;
    if (r < 2) {
      int jj3[3] = { i0, i1, i2 };
      double ww[3] = { w0, w1, w2 };
      for (int j = 0; j < 3; ++j) {
        int slot = (r * 3 + j) * 12 + jj3[j];
        int pos = atomicAdd(&cnt[slot], 1);
        ltok[slot * CAP + pos] = n;
        lwgt[slot * CAP + pos] = (float)ww[j];
      }
    } else {
      se[tok * 3 + 0] = i0; se[tok * 3 + 1] = i1; se[tok * 3 + 2] = i2;
      swg[tok * 3 + 0] = (float)w0; swg[tok * 3 + 1] = (float)w1; swg[tok * 3 + 2] = (float)w2;
    }
  }
  __syncthreads();

  { // bias init of d_out (f32): out[n] = sum_j w3_j * b2[e3_j]
    const int tok = tid >> 3, cg = tid & 7;
    const int n = tok0 + tok;
    const float* r0 = b2 + (size_t)se[tok * 3 + 0] * 1024;
    const float* r1 = b2 + (size_t)se[tok * 3 + 1] * 1024;
    const float* r2 = b2 + (size_t)se[tok * 3 + 2] * 1024;
    const float w0 = swg[tok * 3 + 0], w1 = swg[tok * 3 + 1], w2 = swg[tok * 3 + 2];
    float* op = out + (size_t)n * 1024;
    for (int c = cg * 128; c < cg * 128 + 128; c += 4) {
      float4 a = *(const float4*)(r0 + c);
      float4 b = *(const float4*)(r1 + c);
      float4 d = *(const float4*)(r2 + c);
      float4 o;
      o.x = w0 * a.x + w1 * b.x + w2 * d.x;
      o.y = w0 * a.y + w1 * b.y + w2 * d.y;
      o.z = w0 * a.z + w1 * b.z + w2 * d.z;
      o.w = w0 * a.w + w1 * b.w + w2 * d.w;
      *(float4*)(op + c) = o;
    }
  }
}

// ---------------- tile descriptor build ----------------
__global__ void build_k(const int* __restrict__ cnt, int2* __restrict__ desc,
                        int* __restrict__ ntl) {
  int t = threadIdx.x;
  if (t < 6) {
    int nt = 0;
    for (int e = 0; e < 12; ++e) {
      int c = cnt[t * 12 + e];
      for (int s = 0; s < c; s += 128) { desc[t * 80 + nt] = make_int2(e, s); ++nt; }
    }
    ntl[t] = nt;
  }
}

// ---------------- grouped GEMM pass (m97 structure + T1 + T2) ----------------
// CT = u16 (bf16 RMW, used for h) or float (f32 RMW, used for d_out)
template<int K, int NOUT, bool ADD, typename CT>
__global__ __launch_bounds__(256) void moe_gemm(
    const u16* __restrict__ A, const u16* __restrict__ W, CT* __restrict__ C,
    const int* __restrict__ cnt12, const int* __restrict__ ltok12,
    const float* __restrict__ lwgt12,
    const int2* __restrict__ desc, const int* __restrict__ ntl) {
  // T1: XCD-chunked swizzle (nwg % 8 == 0 for both grids used)
  unsigned lin = blockIdx.y * gridDim.x + blockIdx.x;
  unsigned q = (gridDim.x * gridDim.y) >> 3;
  unsigned swz = (lin & 7) * q + (lin >> 3);
  int tile = swz % gridDim.x;
  int ntile = swz / gridDim.x;
  if (tile >= *ntl) return;
  const int2 dd = desc[tile];
  const int e = dd.x, rowStart = dd.y;
  const int rows = min(128, cnt12[e] - rowStart);

  __shared__ __align__(16) u16 As[128 * 64];
  __shared__ __align__(16) u16 Bs[128 * 64];
  __shared__ int tokL[128];
  __shared__ float wgtL[128];

  const int tid = threadIdx.x;
  const int lane = tid & 63, w = tid >> 6;
  if (tid < 128) {
    int li = min(tid, rows - 1);
    tokL[tid] = ltok12[e * CAP + rowStart + li];
    wgtL[tid] = lwgt12[e * CAP + rowStart + li];
  }
  __syncthreads();

  // T2 staging: linear LDS dest, inverse-swizzled global source column
  const int srcOff = (((lane & 7) ^ (lane >> 3)) * 8);
  const u16* aSrc[4]; const u16* bSrc[4];
#pragma unroll
  for (int i = 0; i < 4; ++i) {
    int r = (w * 4 + i) * 8 + (lane >> 3);
    aSrc[i] = A + (size_t)tokL[r] * K + srcOff;
    bSrc[i] = W + ((size_t)e * NOUT + ntile * 128 + r) * K + srcOff;
  }

  f32x4 acc[4][4] = {};
  const int wr = w >> 1, wc = w & 1;
  const int sx = (lane & 7) << 3;       // T2 read-side XOR (u16 units)
  const int hi8 = (lane >> 4) * 8;

  for (int kt = 0; kt < K / 64; ++kt) {
#pragma unroll
    for (int i = 0; i < 4; ++i) {
      int c = w * 4 + i;
      async16(aSrc[i] + kt * 64, &As[c * 512]);
      async16(bSrc[i] + kt * 64, &Bs[c * 512]);
    }
    asm volatile("s_waitcnt vmcnt(0)" ::: "memory");
    __syncthreads();
#pragma unroll
    for (int kk = 0; kk < 2; ++kk) {
      bf16x8 af[4], bfr[4];
#pragma unroll
      for (int mi = 0; mi < 4; ++mi) {
        int rowA = wr * 64 + mi * 16 + (lane & 15);
        af[mi] = *(const bf16x8*)&As[rowA * 64 + ((kk * 32 + hi8) ^ sx)];
      }
#pragma unroll
      for (int ni = 0; ni < 4; ++ni) {
        int rowB = wc * 64 + ni * 16 + (lane & 15);
        bfr[ni] = *(const bf16x8*)&Bs[rowB * 64 + ((kk * 32 + hi8) ^ sx)];
      }
#pragma unroll
      for (int mi = 0; mi < 4; ++mi)
#pragma unroll
        for (int ni = 0; ni < 4; ++ni)
          acc[mi][ni] = __builtin_amdgcn_mfma_f32_16x16x32_bf16(af[mi], bfr[ni], acc[mi][ni], 0, 0, 0);
    }
    __syncthreads();
  }

  // epilogue: scaled scatter (RMW; bf16 pair-packed u32, f32 scalar)
#pragma unroll
  for (int mi = 0; mi < 4; ++mi) {
    int lr0 = wr * 64 + mi * 16 + ((lane >> 4) << 2);
#pragma unroll
    for (int rr = 0; rr < 4; ++rr) {
      int lrow = lr0 + rr;
      bool rowok = lrow < rows;
      int tok = tokL[lrow];
      float wv = wgtL[lrow];
      if constexpr (sizeof(CT) == 2) {
        u32* cp32 = (u32*)((u16*)C + (size_t)tok * NOUT + ntile * 128 + wc * 64 + (lane & 14));
#pragma unroll
        for (int ni = 0; ni < 4; ++ni) {
          float v = acc[mi][ni][rr] * wv;
          float vo = __shfl_xor(v, 1);
          if (rowok && !(lane & 1)) {
            float lo = v, hi = vo;
            if (ADD) {
              u32 cur = cp32[ni * 8];
              lo += b2f((u16)(cur & 0xffffu));
              hi += b2f((u16)(cur >> 16));
            }
            cp32[ni * 8] = (u32)f2b(lo) | ((u32)f2b(hi) << 16);
          }
        }
      } else {
        if (rowok) {
          float* cp = (float*)C + (size_t)tok * NOUT + ntile * 128 + wc * 64 + (lane & 15);
#pragma unroll
          for (int ni = 0; ni < 4; ++ni) {
            float val = acc[mi][ni][rr] * wv;
            float* p = cp + ni * 16;
            *p = ADD ? (*p + val) : val;
          }
        }
      }
    }
  }
}

// ---------------- exact GELU in-place on bf16 h ----------------
DEVI float gelu1(float v) { return 0.5f * v * (1.0f + erff(v * 0.70710678118654752f)); }
DEVI u32 gpair(u32 u) {
  float lo = __builtin_bit_cast(float, (u & 0xffffu) << 16);
  float hi = __builtin_bit_cast(float, u & 0xffff0000u);
  return (u32)f2b(gelu1(lo)) | ((u32)f2b(gelu1(hi)) << 16);
}
__global__ void gelu_k(u32* __restrict__ h, long n4) {
  long stride = (long)gridDim.x * blockDim.x;
  uint4* p = (uint4*)h;
  for (long i = (long)blockIdx.x * blockDim.x + threadIdx.x; i < n4; i += stride) {
    uint4 v = p[i];
    v.x = gpair(v.x); v.y = gpair(v.y); v.z = gpair(v.z); v.w = gpair(v.w);
    p[i] = v;
  }
}

extern "C" void kernel_launch(void* const* d_in, const int* in_sizes, int n_in,
                              void* d_out, int out_size, void* d_ws, size_t ws_size,
                              hipStream_t stream) {
  const float* x  = (const float*)d_in[0];
  const float* Pw = (const float*)d_in[1];
  const float* U1 = (const float*)d_in[2];
  const float* U2 = (const float*)d_in[3];
  const float* U3 = (const float*)d_in[4];
  const float* W1 = (const float*)d_in[5];
  const float* W2 = (const float*)d_in[6];
  const float* b2 = (const float*)d_in[7];
  float* out = (float*)d_out;

  char* ws = (char*)d_ws;
  size_t o = 0;
  u16* Wb = (u16*)(ws + o); o += (size_t)12 * 4096 * 1024 * 2;  // W1b, later W2b
  u16* xb = (u16*)(ws + o); o += (size_t)8192 * 1024 * 2;
  u16* h  = (u16*)(ws + o); o += (size_t)8192 * 4096 * 2;
  int* cnt = (int*)(ws + o); o += 512;
  int2* desc = (int2*)(ws + o); o += (size_t)6 * 80 * sizeof(int2);
  o = (o + 255) & ~(size_t)255;
  int* ntl = (int*)(ws + o); o += 256;
  int* ltok = (int*)(ws + o); o += (size_t)6 * 12 * CAP * 4;
  float* lwgt = (float*)(ws + o); o += (size_t)6 * 12 * CAP * 4;
  if (ws_size < o) return;

  hipMemsetAsync(cnt, 0, 512, stream);
  cvt_k<<<4096, 256, 0, stream>>>(W1, Wb, (long)12 * 4096 * 1024);
  router_k<<<256, 256, 0, stream>>>(x, Pw, U1, U2, U3, b2, cnt, ltok, lwgt, out, xb);
  build_k<<<1, 64, 0, stream>>>(cnt, desc, ntl);

  { // layer 1: h = sum over ranks of w * (x @ W1[e]^T)   (bf16 RMW in ws)
    dim3 g(80, 32);
    int s;
    s = 0; moe_gemm<1024, 4096, false, u16><<<g, 256, 0, stream>>>(xb, Wb, h, cnt + s * 12, ltok + (size_t)s * 12 * CAP, lwgt + (size_t)s * 12 * CAP, desc + s * 80, ntl + s);
    s = 1; moe_gemm<1024, 4096, true , u16><<<g, 256, 0, stream>>>(xb, Wb, h, cnt + s * 12, ltok + (size_t)s * 12 * CAP, lwgt + (size_t)s * 12 * CAP, desc + s * 80, ntl + s);
    s = 2; moe_gemm<1024, 4096, true , u16><<<g, 256, 0, stream>>>(xb, Wb, h, cnt + s * 12, ltok + (size_t)s * 12 * CAP, lwgt + (size_t)s * 12 * CAP, desc + s * 80, ntl + s);
  }

  cvt_k<<<4096, 256, 0, stream>>>(W2, Wb, (long)12 * 1024 * 4096);
  gelu_k<<<2048, 256, 0, stream>>>((u32*)h, (long)8192 * 4096 / 8);

  { // layer 2: out += sum over ranks of w * (gelu(h) @ W2[e]^T)   (bias already in out, f32)
    dim3 g(80, 8);
    int s;
    s = 3; moe_gemm<4096, 1024, true, float><<<g, 256, 0, stream>>>(h, Wb, out, cnt + s * 12, ltok + (size_t)s * 12 * CAP, lwgt + (size_t)s * 12 * CAP, desc + s * 80, ntl + s);
    s = 4; moe_gemm<4096, 1024, true, float><<<g, 256, 0, stream>>>(h, Wb, out, cnt + s * 12, ltok + (size_t)s * 12 * CAP, lwgt + (size_t)s * 12 * CAP, desc + s * 80, ntl + s);
    s = 5; moe_gemm<4096, 1024, true, float><<<g, 256, 0, stream>>>(h, Wb, out, cnt + s * 12, ltok + (size_t)s * 12 * CAP, lwgt + (size_t)s * 12 * CAP, desc + s * 80, ntl + s);
  }
}